// Round 20
// baseline (89.607 us; speedup 1.0000x reference)
//
#include <hip/hip_runtime.h>
#include <hip/hip_bf16.h>
#include <hip/hip_fp16.h>
#include <math.h>

#define N_NODES 20000
#define N_EDGES 320000
#define E_TOT   (N_EDGES + N_NODES)
#define N_FEAT  128
#define NEG_SLOPE 0.2f
#define SEG     64   // per-XCD per-node segment capacity; >= max in-degree (~50) so
                     // no overflow regardless of block->XCD scheduling

typedef _Float16 half8 __attribute__((ext_vector_type(8)));
typedef float f32x4 __attribute__((ext_vector_type(4)));

// ---- init: zero 8 per-XCD cursor planes + W1 fp16-transpose ----
__global__ void k_init(int* __restrict__ cur8,
                       const float* __restrict__ W1, _Float16* __restrict__ W1t){
  int tid = blockIdx.x * blockDim.x + threadIdx.x;
  if (tid < 8 * N_NODES) cur8[tid] = 0;
  if (tid < 4096){                             // W1t[256 n][128 k]
    int n = tid >> 4, ks = tid & 15;
    union { __half2 h2[4]; half8 h8; } u;
    float v[8];
    #pragma unroll
    for (int r = 0; r < 8; ++r) v[r] = W1[(size_t)(ks * 8 + r) * 256 + n];
    u.h2[0] = __floats2half2_rn(v[0], v[1]);
    u.h2[1] = __floats2half2_rn(v[2], v[3]);
    u.h2[2] = __floats2half2_rn(v[4], v[5]);
    u.h2[3] = __floats2half2_rn(v[6], v[7]);
    *(half8*)&W1t[(size_t)n * 128 + ks * 8] = u.h8;
  }
}

// ---- GEMM1 via MFMA fp16, 2 heads/block + XCD-LOCAL adjacency scatter.
// Device-scope atomics serialize at the MALL (~3.5/cy device-wide, R17-R19
// analysis). Here each wave scatters into ITS OWN XCD's plane with
// workgroup-scope atomics -> RMW executes in the local (coherent-for-this-
// plane) L2 instead of the MALL.
__global__ __launch_bounds__(256) void k_gemm1(
                        const float* __restrict__ x, const _Float16* __restrict__ W1t,
                        const float* __restrict__ as1, const float* __restrict__ ad1,
                        _Float16* __restrict__ h1h,
                        float* __restrict__ alS, float* __restrict__ alD,
                        const int* __restrict__ ei, int* __restrict__ cur8,
                        int* __restrict__ adjS8){
  __shared__ _Float16 xt[64][136];    // [m][k], pad 8 halves
  __shared__ _Float16 Wt[128][136];   // [n][k] for 2 heads
  int t  = threadIdx.x;

  // --- per-XCD padded-adjacency build ---
  {
    int xcd;
    asm volatile("s_getreg_b32 %0, hwreg(HW_REG_XCC_ID)" : "=s"(xcd));
    xcd &= 7;
    int* __restrict__ curp = cur8 + xcd * N_NODES;
    int* __restrict__ adjp = adjS8 + (size_t)xcd * N_NODES * SEG;
    int fb = blockIdx.y * 313 + blockIdx.x;
    int gtid = fb * 256 + t;
    const int GSZ = 313 * 2 * 256;   // 160256 threads; e0,e1 always valid
    int e0 = gtid, e1 = gtid + GSZ, e2 = gtid + 2 * GSZ;
    bool k2 = (e2 < E_TOT);
    int s0, d0, s1, d1, s2 = 0, d2 = 0;
    if (e0 < N_EDGES){ s0 = ei[e0]; d0 = ei[N_EDGES + e0]; } else { s0 = d0 = e0 - N_EDGES; }
    if (e1 < N_EDGES){ s1 = ei[e1]; d1 = ei[N_EDGES + e1]; } else { s1 = d1 = e1 - N_EDGES; }
    if (k2){
      if (e2 < N_EDGES){ s2 = ei[e2]; d2 = ei[N_EDGES + e2]; } else { s2 = d2 = e2 - N_EDGES; }
    }
    int p0 = __hip_atomic_fetch_add(&curp[d0], 1, __ATOMIC_RELAXED, __HIP_MEMORY_SCOPE_WORKGROUP);
    int p1 = __hip_atomic_fetch_add(&curp[d1], 1, __ATOMIC_RELAXED, __HIP_MEMORY_SCOPE_WORKGROUP);
    int p2 = k2 ? __hip_atomic_fetch_add(&curp[d2], 1, __ATOMIC_RELAXED, __HIP_MEMORY_SCOPE_WORKGROUP) : 0;
    if (p0 < SEG) adjp[(size_t)d0 * SEG + p0] = s0;
    if (p1 < SEG) adjp[(size_t)d1 * SEG + p1] = s1;
    if (k2 && p2 < SEG) adjp[(size_t)d2 * SEG + p2] = s2;
  }

  int m0 = blockIdx.x * 64;
  int by = blockIdx.y;               // head pair: heads 2*by, 2*by+1
  int j0 = by * 128;
  // stage x (fp32 -> fp16 in-register)
  #pragma unroll
  for (int ii = 0; ii < 4; ++ii){
    int f = t + ii * 256;            // 1024 slots = 64 rows x 16 half8
    int r = f >> 4, s = f & 15;
    half8 xv = (half8)(_Float16)0.f;
    if (m0 + r < N_NODES){
      float4 a = *(const float4*)&x[(size_t)(m0 + r) * 128 + s * 8];
      float4 bq = *(const float4*)&x[(size_t)(m0 + r) * 128 + s * 8 + 4];
      union { __half2 h2[4]; half8 h8; } u;
      u.h2[0] = __floats2half2_rn(a.x, a.y);
      u.h2[1] = __floats2half2_rn(a.z, a.w);
      u.h2[2] = __floats2half2_rn(bq.x, bq.y);
      u.h2[3] = __floats2half2_rn(bq.z, bq.w);
      xv = u.h8;
    }
    *(half8*)&xt[r][s * 8] = xv;
  }
  // stage W1t rows (coalesced half8 loads, 16B ds writes)
  #pragma unroll
  for (int ii = 0; ii < 8; ++ii){
    int f = t + ii * 256;            // 2048 slots = 128 rows x 16 half8
    int r = f >> 4, s = f & 15;
    half8 wv = *(const half8*)&W1t[(size_t)(j0 + r) * 128 + s * 8];
    *(half8*)&Wt[r][s * 8] = wv;
  }
  __syncthreads();

  int w = t >> 6, lane = t & 63;
  int g = lane >> 4, mi = lane & 15;
  f32x4 acc[8] = {};
  #pragma unroll
  for (int kk = 0; kk < 4; ++kk){
    int ko = kk * 32 + g * 8;
    half8 b = *(const half8*)&xt[w * 16 + mi][ko];
    #pragma unroll
    for (int s = 0; s < 8; ++s){
      half8 a = *(const half8*)&Wt[s * 16 + mi][ko];
      acc[s] = __builtin_amdgcn_mfma_f32_16x16x32_f16(a, b, acc[s], 0, 0, 0);
    }
  }

  int m = m0 + w * 16 + mi;
  float sA = 0.f, dA = 0.f, sB = 0.f, dB = 0.f;
  #pragma unroll
  for (int s = 0; s < 8; ++s){
    int nb = j0 + s * 16 + g * 4;
    float4 asv = *(const float4*)&as1[nb];
    float4 adv = *(const float4*)&ad1[nb];
    float sv = acc[s][0] * asv.x + acc[s][1] * asv.y + acc[s][2] * asv.z + acc[s][3] * asv.w;
    float dv = acc[s][0] * adv.x + acc[s][1] * adv.y + acc[s][2] * adv.z + acc[s][3] * adv.w;
    if (s < 4){ sA += sv; dA += dv; } else { sB += sv; dB += dv; }
    if (m < N_NODES){
      union { __half2 h2[2]; float2 f2; } u;
      u.h2[0] = __floats2half2_rn(acc[s][0], acc[s][1]);
      u.h2[1] = __floats2half2_rn(acc[s][2], acc[s][3]);
      *(float2*)&h1h[(size_t)m * 256 + nb] = u.f2;
    }
  }
  sA += __shfl_xor(sA, 16); sA += __shfl_xor(sA, 32);
  dA += __shfl_xor(dA, 16); dA += __shfl_xor(dA, 32);
  sB += __shfl_xor(sB, 16); sB += __shfl_xor(sB, 32);
  dB += __shfl_xor(dB, 16); dB += __shfl_xor(dB, 32);
  if (g == 0 && m < N_NODES){
    int h0 = by * 2, h1 = by * 2 + 1;
    alS[(size_t)h0 * N_NODES + m] = sA; alD[(size_t)h0 * N_NODES + m] = dA;
    alS[(size_t)h1 * N_NODES + m] = sB; alD[(size_t)h1 * N_NODES + m] = dB;
  }
}

// ---- layer-1 single-pass softmax+aggregate+bias+ELU (planar alS/alD,
// 8-segment per-XCD adjacency; halves split segments by parity, 2-edge ILP) ----
__global__ __launch_bounds__(256) void k_attn1(
                        const int* __restrict__ cur8, const int* __restrict__ adjS8,
                        const __half* __restrict__ h1h,
                        const float* __restrict__ alS, const float* __restrict__ alD,
                        const float* __restrict__ b1, _Float16* __restrict__ heluh){
  int b    = blockIdx.x;
  int slot = b & 7;
  int h    = slot & 3;
  int g    = (slot >> 2) * 625 + (b >> 3);    // node group [0,1250)
  int t    = threadIdx.x;
  int w    = t >> 6, lane = t & 63;
  int grp  = lane >> 4, l16 = lane & 15;
  int hf   = l16 >> 3, l8 = l16 & 7;
  int n    = g * 16 + w * 4 + grp;

  const float* __restrict__ alSp = alS + (size_t)h * N_NODES;
  float ald = alD[(size_t)h * N_NODES + n];
  const __half* __restrict__ hb = h1h + h * 64 + l8 * 8;

  float4 Aa = make_float4(0.f,0.f,0.f,0.f), Ab = Aa;
  float den = 0.f;

  for (int xs = hf; xs < 8; xs += 2){
    int cnt = cur8[xs * N_NODES + n]; cnt = (cnt > SEG) ? SEG : cnt;
    const int* __restrict__ ap = adjS8 + ((size_t)xs * N_NODES + n) * SEG;
    int i = 0;
    for (; i + 1 < cnt; i += 2){
      int s0 = ap[i], s1 = ap[i + 1];
      float t0 = alSp[s0] + ald;
      float t1 = alSp[s1] + ald;
      t0 = (t0 > 0.f) ? t0 : NEG_SLOPE * t0;
      t1 = (t1 > 0.f) ? t1 : NEG_SLOPE * t1;
      float w0 = __expf(t0), w1 = __expf(t1);
      float4 r0 = *(const float4*)&hb[(size_t)s0 * 256];
      float4 r1 = *(const float4*)&hb[(size_t)s1 * 256];
      const __half2* p0 = (const __half2*)&r0;
      const __half2* p1 = (const __half2*)&r1;
      {
        float2 a0 = __half22float2(p0[0]), a1 = __half22float2(p0[1]);
        float2 a2 = __half22float2(p0[2]), a3 = __half22float2(p0[3]);
        Aa.x += w0 * a0.x; Aa.y += w0 * a0.y; Aa.z += w0 * a1.x; Aa.w += w0 * a1.y;
        Ab.x += w0 * a2.x; Ab.y += w0 * a2.y; Ab.z += w0 * a3.x; Ab.w += w0 * a3.y;
      }
      {
        float2 a0 = __half22float2(p1[0]), a1 = __half22float2(p1[1]);
        float2 a2 = __half22float2(p1[2]), a3 = __half22float2(p1[3]);
        Aa.x += w1 * a0.x; Aa.y += w1 * a0.y; Aa.z += w1 * a1.x; Aa.w += w1 * a1.y;
        Ab.x += w1 * a2.x; Ab.y += w1 * a2.y; Ab.z += w1 * a3.x; Ab.w += w1 * a3.y;
      }
      den += (w0 + w1);
    }
    if (i < cnt){
      int s0 = ap[i];
      float t0 = alSp[s0] + ald;
      t0 = (t0 > 0.f) ? t0 : NEG_SLOPE * t0;
      float w0 = __expf(t0);
      float4 r0 = *(const float4*)&hb[(size_t)s0 * 256];
      const __half2* p0 = (const __half2*)&r0;
      float2 a0 = __half22float2(p0[0]), a1 = __half22float2(p0[1]);
      float2 a2 = __half22float2(p0[2]), a3 = __half22float2(p0[3]);
      Aa.x += w0 * a0.x; Aa.y += w0 * a0.y; Aa.z += w0 * a1.x; Aa.w += w0 * a1.y;
      Ab.x += w0 * a2.x; Ab.y += w0 * a2.y; Ab.z += w0 * a3.x; Ab.w += w0 * a3.y;
      den += w0;
    }
  }
  Aa.x += __shfl_xor(Aa.x, 8); Aa.y += __shfl_xor(Aa.y, 8);
  Aa.z += __shfl_xor(Aa.z, 8); Aa.w += __shfl_xor(Aa.w, 8);
  Ab.x += __shfl_xor(Ab.x, 8); Ab.y += __shfl_xor(Ab.y, 8);
  Ab.z += __shfl_xor(Ab.z, 8); Ab.w += __shfl_xor(Ab.w, 8);
  den  += __shfl_xor(den, 8);

  if (hf == 0){
    float rinv = 1.f / (den + 1e-16f);
    float4 bv0 = *(const float4*)&b1[h * 64 + l8 * 8];
    float4 bv1 = *(const float4*)&b1[h * 64 + l8 * 8 + 4];
    float o0 = Aa.x * rinv + bv0.x;
    float o1 = Aa.y * rinv + bv0.y;
    float o2 = Aa.z * rinv + bv0.z;
    float o3 = Aa.w * rinv + bv0.w;
    float o4 = Ab.x * rinv + bv1.x;
    float o5 = Ab.y * rinv + bv1.y;
    float o6 = Ab.z * rinv + bv1.z;
    float o7 = Ab.w * rinv + bv1.w;
    o0 = (o0 > 0.f) ? o0 : (__expf(o0) - 1.f);
    o1 = (o1 > 0.f) ? o1 : (__expf(o1) - 1.f);
    o2 = (o2 > 0.f) ? o2 : (__expf(o2) - 1.f);
    o3 = (o3 > 0.f) ? o3 : (__expf(o3) - 1.f);
    o4 = (o4 > 0.f) ? o4 : (__expf(o4) - 1.f);
    o5 = (o5 > 0.f) ? o5 : (__expf(o5) - 1.f);
    o6 = (o6 > 0.f) ? o6 : (__expf(o6) - 1.f);
    o7 = (o7 > 0.f) ? o7 : (__expf(o7) - 1.f);
    union { __half2 h2[4]; half8 h8; } u;
    u.h2[0] = __floats2half2_rn(o0, o1);
    u.h2[1] = __floats2half2_rn(o2, o3);
    u.h2[2] = __floats2half2_rn(o4, o5);
    u.h2[3] = __floats2half2_rn(o6, o7);
    *(half8*)&heluh[(size_t)n * 256 + h * 64 + l8 * 8] = u.h8;
  }
}

// ---- GEMM2 via MFMA fp16 (unchanged) ----
__global__ __launch_bounds__(256) void k_gemm2(
                        const _Float16* __restrict__ heluh, const float* __restrict__ W2,
                        const float* __restrict__ as2, const float* __restrict__ ad2,
                        float* __restrict__ h2, float* __restrict__ alS, float* __restrict__ alD){
  __shared__ _Float16 Ht[64][264];   // [node][k], pad 8
  __shared__ _Float16 Wt[16][264];   // [col][k]
  int t = threadIdx.x;
  int n0 = blockIdx.x * 64;
  #pragma unroll
  for (int ii = 0; ii < 8; ++ii){
    int f = t + ii * 256;            // 2048 slots = 64 rows x 32 half8
    int r = f >> 5, s = f & 31;
    half8 v = (half8)(_Float16)0.f;
    if (n0 + r < N_NODES) v = *(const half8*)&heluh[(size_t)(n0 + r) * 256 + s * 8];
    *(half8*)&Ht[r][s * 8] = v;
  }
  {                                   // W2 [256 k][16 col] fp32 -> Wt[16][256] fp16
    int k = t;
    float4 w0 = *(const float4*)&W2[k * 16 + 0];
    float4 w1 = *(const float4*)&W2[k * 16 + 4];
    float4 w2 = *(const float4*)&W2[k * 16 + 8];
    float4 w3 = *(const float4*)&W2[k * 16 + 12];
    float wv[16] = {w0.x,w0.y,w0.z,w0.w, w1.x,w1.y,w1.z,w1.w,
                    w2.x,w2.y,w2.z,w2.w, w3.x,w3.y,w3.z,w3.w};
    #pragma unroll
    for (int c = 0; c < 16; ++c) Wt[c][k] = (_Float16)wv[c];
  }
  __syncthreads();

  int w = t >> 6, lane = t & 63;
  int g = lane >> 4, mi = lane & 15;
  f32x4 acc = {};
  #pragma unroll
  for (int kk = 0; kk < 8; ++kk){
    int ko = kk * 32 + g * 8;
    half8 b = *(const half8*)&Ht[w * 16 + mi][ko];
    half8 a = *(const half8*)&Wt[mi][ko];
    acc = __builtin_amdgcn_mfma_f32_16x16x32_f16(a, b, acc, 0, 0, 0);
  }
  int n = n0 + w * 16 + mi;
  float4 asv = *(const float4*)&as2[g * 4];
  float4 adv = *(const float4*)&ad2[g * 4];
  float s_ = acc[0] * asv.x + acc[1] * asv.y + acc[2] * asv.z + acc[3] * asv.w;
  float d_ = acc[0] * adv.x + acc[1] * adv.y + acc[2] * adv.z + acc[3] * adv.w;
  s_ += __shfl_xor(s_, 16); s_ += __shfl_xor(s_, 32);
  d_ += __shfl_xor(d_, 16); d_ += __shfl_xor(d_, 32);
  if (n < N_NODES){
    float4 hv = make_float4(acc[0], acc[1], acc[2], acc[3]);
    *(float4*)&h2[(size_t)n * 16 + g * 4] = hv;   // pre-bias
    if (g == 0){ alS[n] = s_; alD[n] = d_; }
  }
}

// ---- layer-2 single-pass softmax+aggregate+bias -> d_out (segmented adjacency;
// j-slots split the 8 segments, c4 spans columns) ----
__global__ __launch_bounds__(256) void k_attn2(
                        const int* __restrict__ cur8, const int* __restrict__ adjS8,
                        const float* __restrict__ h2,
                        const float* __restrict__ alS, const float* __restrict__ alD,
                        const float* __restrict__ b2, float* __restrict__ out){
  int t    = threadIdx.x;
  int w    = t >> 6, lane = t & 63;
  int grp  = lane >> 4, l16 = lane & 15;
  int j    = l16 >> 2, c4 = l16 & 3;
  int n    = blockIdx.x * 16 + w * 4 + grp;

  float ald = alD[n];
  float4 acc = make_float4(0.f,0.f,0.f,0.f);
  float den = 0.f;
  for (int xs = j; xs < 8; xs += 4){
    int cnt = cur8[xs * N_NODES + n]; cnt = (cnt > SEG) ? SEG : cnt;
    const int* __restrict__ ap = adjS8 + ((size_t)xs * N_NODES + n) * SEG;
    for (int i = 0; i < cnt; ++i){
      int s = ap[i];
      float tt = alS[s] + ald;
      tt = (tt > 0.f) ? tt : NEG_SLOPE * tt;
      float wv = __expf(tt);
      float4 v = *(const float4*)&h2[(size_t)s * 16 + c4 * 4];
      acc.x += wv * v.x; acc.y += wv * v.y; acc.z += wv * v.z; acc.w += wv * v.w;
      den += wv;
    }
  }
  #pragma unroll
  for (int off = 4; off <= 8; off <<= 1){
    acc.x += __shfl_xor(acc.x, off);
    acc.y += __shfl_xor(acc.y, off);
    acc.z += __shfl_xor(acc.z, off);
    acc.w += __shfl_xor(acc.w, off);
    den   += __shfl_xor(den, off);
  }
  if (j == 0){
    float rinv = 1.f / (den + 1e-16f);
    float4 bv = *(const float4*)&b2[c4 * 4];
    float4 o;
    o.x = acc.x * rinv + bv.x; o.y = acc.y * rinv + bv.y;
    o.z = acc.z * rinv + bv.z; o.w = acc.w * rinv + bv.w;
    *(float4*)&out[(size_t)n * 16 + c4 * 4] = o;
  }
}

extern "C" void kernel_launch(void* const* d_in, const int* in_sizes, int n_in,
                              void* d_out, int out_size, void* d_ws, size_t ws_size,
                              hipStream_t stream){
  const float* x   = (const float*)d_in[0];
  const int*   ei  = (const int*)d_in[1];
  const float* W1  = (const float*)d_in[2];
  const float* as1 = (const float*)d_in[3];
  const float* ad1 = (const float*)d_in[4];
  const float* b1  = (const float*)d_in[5];
  const float* W2  = (const float*)d_in[6];
  const float* as2 = (const float*)d_in[7];
  const float* ad2 = (const float*)d_in[8];
  const float* b2  = (const float*)d_in[9];
  float* out = (float*)d_out;

  float* fws = (float*)d_ws;
  size_t off = 0;
  __half* h1h = (__half*)(fws + off); off += (size_t)N_NODES * 128;      // fp16 [20000,256]
  _Float16* W1t = (_Float16*)(fws + off); off += 256 * 64;                // fp16 [256,128]
  _Float16* heluh = (_Float16*)(fws + off); off += (size_t)N_NODES * 128; // fp16 [20000,256]
  float* h2   = fws + off; off += (size_t)N_NODES * 16;
  float* alS1 = fws + off; off += N_NODES * 4;   // planar [4][N]
  float* alD1 = fws + off; off += N_NODES * 4;   // planar [4][N]
  float* alS2 = fws + off; off += N_NODES;
  float* alD2 = fws + off; off += N_NODES;
  int* cur8  = (int*)(fws + off); off += (size_t)8 * N_NODES;
  int* adjS8 = (int*)(fws + off); off += (size_t)8 * N_NODES * SEG;

  k_init<<<(8 * N_NODES + 255) / 256, 256, 0, stream>>>(cur8, W1, W1t);
  k_gemm1<<<dim3(313, 2), 256, 0, stream>>>(x, W1t, as1, ad1, (_Float16*)h1h,
                                            alS1, alD1, ei, cur8, adjS8);
  k_attn1<<<5000, 256, 0, stream>>>(cur8, adjS8, h1h, alS1, alD1, b1, heluh);
  k_gemm2<<<313, 256, 0, stream>>>(heluh, W2, as2, ad2, h2, alS2, alD2);
  k_attn2<<<1250, 256, 0, stream>>>(cur8, adjS8, h2, alS2, alD2, b2, out);
}

// Round 21
// 73.236 us; speedup vs baseline: 1.2235x; 1.2235x over previous
//
#include <hip/hip_runtime.h>
#include <hip/hip_bf16.h>
#include <hip/hip_fp16.h>
#include <math.h>

#define N_NODES 20000
#define N_EDGES 320000
#define E_TOT   (N_EDGES + N_NODES)
#define N_FEAT  128
#define NEG_SLOPE 0.2f
#define MAXDEG  64   // padded adjacency stride; in-degree Poisson(17), max ~45-50 << 64
#define CURPAD  16   // one cursor per 64B line

typedef _Float16 half8 __attribute__((ext_vector_type(8)));
typedef float f32x4 __attribute__((ext_vector_type(4)));

// ---- init: zero padded cursor + W1 fp16-transpose (kernel zero: runtime fill
// kernel is pathologically slow at small sizes — 42us vs ~2us here, R14 lesson) ----
__global__ void k_init(int* __restrict__ cur,
                       const float* __restrict__ W1, _Float16* __restrict__ W1t){
  int tid = blockIdx.x * blockDim.x + threadIdx.x;
  if (tid < N_NODES * CURPAD) cur[tid] = 0;
  if (tid < 4096){                             // W1t[256 n][128 k]
    int n = tid >> 4, ks = tid & 15;
    union { __half2 h2[4]; half8 h8; } u;
    float v[8];
    #pragma unroll
    for (int r = 0; r < 8; ++r) v[r] = W1[(size_t)(ks * 8 + r) * 256 + n];
    u.h2[0] = __floats2half2_rn(v[0], v[1]);
    u.h2[1] = __floats2half2_rn(v[2], v[3]);
    u.h2[2] = __floats2half2_rn(v[4], v[5]);
    u.h2[3] = __floats2half2_rn(v[6], v[7]);
    *(half8*)&W1t[(size_t)n * 128 + ks * 8] = u.h8;
  }
}

// ---- GEMM1 via MFMA fp16, 2 heads/block + adjacency build (unrolled scatter) ----
__global__ __launch_bounds__(256) void k_gemm1(
                        const float* __restrict__ x, const _Float16* __restrict__ W1t,
                        const float* __restrict__ as1, const float* __restrict__ ad1,
                        _Float16* __restrict__ h1h,
                        float* __restrict__ alS, float* __restrict__ alD,
                        const int* __restrict__ ei, int* __restrict__ cur,
                        int* __restrict__ adjS){
  __shared__ _Float16 xt[64][136];    // [m][k], pad 8 halves
  __shared__ _Float16 Wt[128][136];   // [n][k] for 2 heads
  int t  = threadIdx.x;

  // --- padded-adjacency build: each thread owns <=3 edges, independent atomics ---
  {
    int fb = blockIdx.y * 313 + blockIdx.x;
    int gtid = fb * 256 + t;
    const int GSZ = 313 * 2 * 256;   // 160256 threads; e0,e1 always valid
    int e0 = gtid, e1 = gtid + GSZ, e2 = gtid + 2 * GSZ;
    bool k2 = (e2 < E_TOT);
    int s0, d0, s1, d1, s2 = 0, d2 = 0;
    if (e0 < N_EDGES){ s0 = ei[e0]; d0 = ei[N_EDGES + e0]; } else { s0 = d0 = e0 - N_EDGES; }
    if (e1 < N_EDGES){ s1 = ei[e1]; d1 = ei[N_EDGES + e1]; } else { s1 = d1 = e1 - N_EDGES; }
    if (k2){
      if (e2 < N_EDGES){ s2 = ei[e2]; d2 = ei[N_EDGES + e2]; } else { s2 = d2 = e2 - N_EDGES; }
    }
    int p0 = atomicAdd(&cur[d0 * CURPAD], 1);
    int p1 = atomicAdd(&cur[d1 * CURPAD], 1);
    int p2 = k2 ? atomicAdd(&cur[d2 * CURPAD], 1) : 0;
    if (p0 < MAXDEG) adjS[d0 * MAXDEG + p0] = s0;
    if (p1 < MAXDEG) adjS[d1 * MAXDEG + p1] = s1;
    if (k2 && p2 < MAXDEG) adjS[d2 * MAXDEG + p2] = s2;
  }

  int m0 = blockIdx.x * 64;
  int by = blockIdx.y;               // head pair: heads 2*by, 2*by+1
  int j0 = by * 128;
  // stage x (fp32 -> fp16 in-register)
  #pragma unroll
  for (int ii = 0; ii < 4; ++ii){
    int f = t + ii * 256;            // 1024 slots = 64 rows x 16 half8
    int r = f >> 4, s = f & 15;
    half8 xv = (half8)(_Float16)0.f;
    if (m0 + r < N_NODES){
      float4 a = *(const float4*)&x[(size_t)(m0 + r) * 128 + s * 8];
      float4 bq = *(const float4*)&x[(size_t)(m0 + r) * 128 + s * 8 + 4];
      union { __half2 h2[4]; half8 h8; } u;
      u.h2[0] = __floats2half2_rn(a.x, a.y);
      u.h2[1] = __floats2half2_rn(a.z, a.w);
      u.h2[2] = __floats2half2_rn(bq.x, bq.y);
      u.h2[3] = __floats2half2_rn(bq.z, bq.w);
      xv = u.h8;
    }
    *(half8*)&xt[r][s * 8] = xv;
  }
  // stage W1t rows (coalesced half8 loads, 16B ds writes)
  #pragma unroll
  for (int ii = 0; ii < 8; ++ii){
    int f = t + ii * 256;            // 2048 slots = 128 rows x 16 half8
    int r = f >> 4, s = f & 15;
    half8 wv = *(const half8*)&W1t[(size_t)(j0 + r) * 128 + s * 8];
    *(half8*)&Wt[r][s * 8] = wv;
  }
  __syncthreads();

  int w = t >> 6, lane = t & 63;
  int g = lane >> 4, mi = lane & 15;
  f32x4 acc[8] = {};
  #pragma unroll
  for (int kk = 0; kk < 4; ++kk){
    int ko = kk * 32 + g * 8;
    half8 b = *(const half8*)&xt[w * 16 + mi][ko];
    #pragma unroll
    for (int s = 0; s < 8; ++s){
      half8 a = *(const half8*)&Wt[s * 16 + mi][ko];
      acc[s] = __builtin_amdgcn_mfma_f32_16x16x32_f16(a, b, acc[s], 0, 0, 0);
    }
  }

  int m = m0 + w * 16 + mi;
  float sA = 0.f, dA = 0.f, sB = 0.f, dB = 0.f;
  #pragma unroll
  for (int s = 0; s < 8; ++s){
    int nb = j0 + s * 16 + g * 4;
    float4 asv = *(const float4*)&as1[nb];
    float4 adv = *(const float4*)&ad1[nb];
    float sv = acc[s][0] * asv.x + acc[s][1] * asv.y + acc[s][2] * asv.z + acc[s][3] * asv.w;
    float dv = acc[s][0] * adv.x + acc[s][1] * adv.y + acc[s][2] * adv.z + acc[s][3] * adv.w;
    if (s < 4){ sA += sv; dA += dv; } else { sB += sv; dB += dv; }
    if (m < N_NODES){
      union { __half2 h2[2]; float2 f2; } u;
      u.h2[0] = __floats2half2_rn(acc[s][0], acc[s][1]);
      u.h2[1] = __floats2half2_rn(acc[s][2], acc[s][3]);
      *(float2*)&h1h[(size_t)m * 256 + nb] = u.f2;
    }
  }
  sA += __shfl_xor(sA, 16); sA += __shfl_xor(sA, 32);
  dA += __shfl_xor(dA, 16); dA += __shfl_xor(dA, 32);
  sB += __shfl_xor(sB, 16); sB += __shfl_xor(sB, 32);
  dB += __shfl_xor(dB, 16); dB += __shfl_xor(dB, 32);
  if (g == 0 && m < N_NODES){
    int h0 = by * 2, h1 = by * 2 + 1;
    alS[(size_t)h0 * N_NODES + m] = sA; alD[(size_t)h0 * N_NODES + m] = dA;
    alS[(size_t)h1 * N_NODES + m] = sB; alD[(size_t)h1 * N_NODES + m] = dB;
  }
}

// ---- layer-1 single-pass softmax+aggregate+bias+ELU (planar alS/alD) ----
__global__ __launch_bounds__(256) void k_attn1(
                        const int* __restrict__ cur, const int* __restrict__ adjS,
                        const __half* __restrict__ h1h,
                        const float* __restrict__ alS, const float* __restrict__ alD,
                        const float* __restrict__ b1, _Float16* __restrict__ heluh){
  int b    = blockIdx.x;
  int slot = b & 7;
  int h    = slot & 3;
  int g    = (slot >> 2) * 625 + (b >> 3);    // node group [0,1250)
  int t    = threadIdx.x;
  int w    = t >> 6, lane = t & 63;
  int grp  = lane >> 4, l16 = lane & 15;
  int hf   = l16 >> 3, l8 = l16 & 7;
  int n    = g * 16 + w * 4 + grp;

  int cnt  = cur[n * CURPAD]; cnt = (cnt > MAXDEG) ? MAXDEG : cnt;
  int base = n * MAXDEG;
  const float* __restrict__ alSp = alS + (size_t)h * N_NODES;
  float ald = alD[(size_t)h * N_NODES + n];
  const __half* __restrict__ hb = h1h + h * 64 + l8 * 8;

  float4 Aa = make_float4(0.f,0.f,0.f,0.f), Ab = Aa;
  float den = 0.f;

  int nq = cnt >> 2;
  for (int q = hf; q < nq; q += 2){
    int4 quad = *(const int4*)&adjS[base + q * 4];   // 16B-aligned
    int s0 = quad.x, s1 = quad.y, s2 = quad.z, s3 = quad.w;
    float t0 = alSp[s0] + ald;
    float t1 = alSp[s1] + ald;
    float t2 = alSp[s2] + ald;
    float t3 = alSp[s3] + ald;
    t0 = (t0 > 0.f) ? t0 : NEG_SLOPE * t0;
    t1 = (t1 > 0.f) ? t1 : NEG_SLOPE * t1;
    t2 = (t2 > 0.f) ? t2 : NEG_SLOPE * t2;
    t3 = (t3 > 0.f) ? t3 : NEG_SLOPE * t3;
    float w0 = __expf(t0), w1 = __expf(t1), w2 = __expf(t2), w3 = __expf(t3);
    float4 r0 = *(const float4*)&hb[(size_t)s0 * 256];
    float4 r1 = *(const float4*)&hb[(size_t)s1 * 256];
    float4 r2 = *(const float4*)&hb[(size_t)s2 * 256];
    float4 r3 = *(const float4*)&hb[(size_t)s3 * 256];
    const __half2* p0 = (const __half2*)&r0;
    const __half2* p1 = (const __half2*)&r1;
    const __half2* p2 = (const __half2*)&r2;
    const __half2* p3 = (const __half2*)&r3;
    {
      float2 a0 = __half22float2(p0[0]), a1 = __half22float2(p0[1]);
      float2 a2 = __half22float2(p0[2]), a3 = __half22float2(p0[3]);
      Aa.x += w0 * a0.x; Aa.y += w0 * a0.y; Aa.z += w0 * a1.x; Aa.w += w0 * a1.y;
      Ab.x += w0 * a2.x; Ab.y += w0 * a2.y; Ab.z += w0 * a3.x; Ab.w += w0 * a3.y;
    }
    {
      float2 a0 = __half22float2(p1[0]), a1 = __half22float2(p1[1]);
      float2 a2 = __half22float2(p1[2]), a3 = __half22float2(p1[3]);
      Aa.x += w1 * a0.x; Aa.y += w1 * a0.y; Aa.z += w1 * a1.x; Aa.w += w1 * a1.y;
      Ab.x += w1 * a2.x; Ab.y += w1 * a2.y; Ab.z += w1 * a3.x; Ab.w += w1 * a3.y;
    }
    {
      float2 a0 = __half22float2(p2[0]), a1 = __half22float2(p2[1]);
      float2 a2 = __half22float2(p2[2]), a3 = __half22float2(p2[3]);
      Aa.x += w2 * a0.x; Aa.y += w2 * a0.y; Aa.z += w2 * a1.x; Aa.w += w2 * a1.y;
      Ab.x += w2 * a2.x; Ab.y += w2 * a2.y; Ab.z += w2 * a3.x; Ab.w += w2 * a3.y;
    }
    {
      float2 a0 = __half22float2(p3[0]), a1 = __half22float2(p3[1]);
      float2 a2 = __half22float2(p3[2]), a3 = __half22float2(p3[3]);
      Aa.x += w3 * a0.x; Aa.y += w3 * a0.y; Aa.z += w3 * a1.x; Aa.w += w3 * a1.y;
      Ab.x += w3 * a2.x; Ab.y += w3 * a2.y; Ab.z += w3 * a3.x; Ab.w += w3 * a3.y;
    }
    den += ((w0 + w1) + (w2 + w3));
  }
  if ((nq & 1) == hf){
    for (int i = base + nq * 4; i < base + cnt; ++i){
      int s0 = adjS[i];
      float t0 = alSp[s0] + ald;
      t0 = (t0 > 0.f) ? t0 : NEG_SLOPE * t0;
      float w0 = __expf(t0);
      float4 r0 = *(const float4*)&hb[(size_t)s0 * 256];
      const __half2* p0 = (const __half2*)&r0;
      float2 a0 = __half22float2(p0[0]), a1 = __half22float2(p0[1]);
      float2 a2 = __half22float2(p0[2]), a3 = __half22float2(p0[3]);
      Aa.x += w0 * a0.x; Aa.y += w0 * a0.y; Aa.z += w0 * a1.x; Aa.w += w0 * a1.y;
      Ab.x += w0 * a2.x; Ab.y += w0 * a2.y; Ab.z += w0 * a3.x; Ab.w += w0 * a3.y;
      den += w0;
    }
  }
  Aa.x += __shfl_xor(Aa.x, 8); Aa.y += __shfl_xor(Aa.y, 8);
  Aa.z += __shfl_xor(Aa.z, 8); Aa.w += __shfl_xor(Aa.w, 8);
  Ab.x += __shfl_xor(Ab.x, 8); Ab.y += __shfl_xor(Ab.y, 8);
  Ab.z += __shfl_xor(Ab.z, 8); Ab.w += __shfl_xor(Ab.w, 8);
  den  += __shfl_xor(den, 8);

  if (hf == 0){
    float rinv = 1.f / (den + 1e-16f);
    float4 bv0 = *(const float4*)&b1[h * 64 + l8 * 8];
    float4 bv1 = *(const float4*)&b1[h * 64 + l8 * 8 + 4];
    float o0 = Aa.x * rinv + bv0.x;
    float o1 = Aa.y * rinv + bv0.y;
    float o2 = Aa.z * rinv + bv0.z;
    float o3 = Aa.w * rinv + bv0.w;
    float o4 = Ab.x * rinv + bv1.x;
    float o5 = Ab.y * rinv + bv1.y;
    float o6 = Ab.z * rinv + bv1.z;
    float o7 = Ab.w * rinv + bv1.w;
    o0 = (o0 > 0.f) ? o0 : (__expf(o0) - 1.f);
    o1 = (o1 > 0.f) ? o1 : (__expf(o1) - 1.f);
    o2 = (o2 > 0.f) ? o2 : (__expf(o2) - 1.f);
    o3 = (o3 > 0.f) ? o3 : (__expf(o3) - 1.f);
    o4 = (o4 > 0.f) ? o4 : (__expf(o4) - 1.f);
    o5 = (o5 > 0.f) ? o5 : (__expf(o5) - 1.f);
    o6 = (o6 > 0.f) ? o6 : (__expf(o6) - 1.f);
    o7 = (o7 > 0.f) ? o7 : (__expf(o7) - 1.f);
    union { __half2 h2[4]; half8 h8; } u;
    u.h2[0] = __floats2half2_rn(o0, o1);
    u.h2[1] = __floats2half2_rn(o2, o3);
    u.h2[2] = __floats2half2_rn(o4, o5);
    u.h2[3] = __floats2half2_rn(o6, o7);
    *(half8*)&heluh[(size_t)n * 256 + h * 64 + l8 * 8] = u.h8;
  }
}

// ---- GEMM2 via MFMA fp16 (h2 fp32) ----
__global__ __launch_bounds__(256) void k_gemm2(
                        const _Float16* __restrict__ heluh, const float* __restrict__ W2,
                        const float* __restrict__ as2, const float* __restrict__ ad2,
                        float* __restrict__ h2, float* __restrict__ alS, float* __restrict__ alD){
  __shared__ _Float16 Ht[64][264];   // [node][k], pad 8
  __shared__ _Float16 Wt[16][264];   // [col][k]
  int t = threadIdx.x;
  int n0 = blockIdx.x * 64;
  #pragma unroll
  for (int ii = 0; ii < 8; ++ii){
    int f = t + ii * 256;            // 2048 slots = 64 rows x 32 half8
    int r = f >> 5, s = f & 31;
    half8 v = (half8)(_Float16)0.f;
    if (n0 + r < N_NODES) v = *(const half8*)&heluh[(size_t)(n0 + r) * 256 + s * 8];
    *(half8*)&Ht[r][s * 8] = v;
  }
  {                                   // W2 [256 k][16 col] fp32 -> Wt[16][256] fp16
    int k = t;
    float4 w0 = *(const float4*)&W2[k * 16 + 0];
    float4 w1 = *(const float4*)&W2[k * 16 + 4];
    float4 w2 = *(const float4*)&W2[k * 16 + 8];
    float4 w3 = *(const float4*)&W2[k * 16 + 12];
    float wv[16] = {w0.x,w0.y,w0.z,w0.w, w1.x,w1.y,w1.z,w1.w,
                    w2.x,w2.y,w2.z,w2.w, w3.x,w3.y,w3.z,w3.w};
    #pragma unroll
    for (int c = 0; c < 16; ++c) Wt[c][k] = (_Float16)wv[c];
  }
  __syncthreads();

  int w = t >> 6, lane = t & 63;
  int g = lane >> 4, mi = lane & 15;
  f32x4 acc = {};
  #pragma unroll
  for (int kk = 0; kk < 8; ++kk){
    int ko = kk * 32 + g * 8;
    half8 b = *(const half8*)&Ht[w * 16 + mi][ko];
    half8 a = *(const half8*)&Wt[mi][ko];
    acc = __builtin_amdgcn_mfma_f32_16x16x32_f16(a, b, acc, 0, 0, 0);
  }
  int n = n0 + w * 16 + mi;
  float4 asv = *(const float4*)&as2[g * 4];
  float4 adv = *(const float4*)&ad2[g * 4];
  float s_ = acc[0] * asv.x + acc[1] * asv.y + acc[2] * asv.z + acc[3] * asv.w;
  float d_ = acc[0] * adv.x + acc[1] * adv.y + acc[2] * adv.z + acc[3] * adv.w;
  s_ += __shfl_xor(s_, 16); s_ += __shfl_xor(s_, 32);
  d_ += __shfl_xor(d_, 16); d_ += __shfl_xor(d_, 32);
  if (n < N_NODES){
    float4 hv = make_float4(acc[0], acc[1], acc[2], acc[3]);
    *(float4*)&h2[(size_t)n * 16 + g * 4] = hv;   // pre-bias
    if (g == 0){ alS[n] = s_; alD[n] = d_; }
  }
}

// ---- layer-2 single-pass softmax+aggregate+bias -> d_out ----
__global__ __launch_bounds__(256) void k_attn2(
                        const int* __restrict__ cur, const int* __restrict__ adjS,
                        const float* __restrict__ h2,
                        const float* __restrict__ alS, const float* __restrict__ alD,
                        const float* __restrict__ b2, float* __restrict__ out){
  int t    = threadIdx.x;
  int w    = t >> 6, lane = t & 63;
  int grp  = lane >> 4, l16 = lane & 15;
  int j    = l16 >> 2, c4 = l16 & 3;
  int n    = blockIdx.x * 16 + w * 4 + grp;

  int cnt  = cur[n * CURPAD]; cnt = (cnt > MAXDEG) ? MAXDEG : cnt;
  int start = n * MAXDEG, end = start + cnt;
  float ald = alD[n];
  float4 acc = make_float4(0.f,0.f,0.f,0.f);
  float den = 0.f;
  for (int i = start + j; i < end; i += 4){
    int s = adjS[i];
    float tt = alS[s] + ald;
    tt = (tt > 0.f) ? tt : NEG_SLOPE * tt;
    float wv = __expf(tt);
    float4 v = *(const float4*)&h2[(size_t)s * 16 + c4 * 4];
    acc.x += wv * v.x; acc.y += wv * v.y; acc.z += wv * v.z; acc.w += wv * v.w;
    den += wv;
  }
  #pragma unroll
  for (int off = 4; off <= 8; off <<= 1){
    acc.x += __shfl_xor(acc.x, off);
    acc.y += __shfl_xor(acc.y, off);
    acc.z += __shfl_xor(acc.z, off);
    acc.w += __shfl_xor(acc.w, off);
    den   += __shfl_xor(den, off);
  }
  if (j == 0){
    float rinv = 1.f / (den + 1e-16f);
    float4 bv = *(const float4*)&b2[c4 * 4];
    float4 o;
    o.x = acc.x * rinv + bv.x; o.y = acc.y * rinv + bv.y;
    o.z = acc.z * rinv + bv.z; o.w = acc.w * rinv + bv.w;
    *(float4*)&out[(size_t)n * 16 + c4 * 4] = o;
  }
}

extern "C" void kernel_launch(void* const* d_in, const int* in_sizes, int n_in,
                              void* d_out, int out_size, void* d_ws, size_t ws_size,
                              hipStream_t stream){
  const float* x   = (const float*)d_in[0];
  const int*   ei  = (const int*)d_in[1];
  const float* W1  = (const float*)d_in[2];
  const float* as1 = (const float*)d_in[3];
  const float* ad1 = (const float*)d_in[4];
  const float* b1  = (const float*)d_in[5];
  const float* W2  = (const float*)d_in[6];
  const float* as2 = (const float*)d_in[7];
  const float* ad2 = (const float*)d_in[8];
  const float* b2  = (const float*)d_in[9];
  float* out = (float*)d_out;

  float* fws = (float*)d_ws;
  size_t off = 0;
  __half* h1h = (__half*)(fws + off); off += (size_t)N_NODES * 128;      // fp16 [20000,256]
  _Float16* W1t = (_Float16*)(fws + off); off += 256 * 64;                // fp16 [256,128]
  _Float16* heluh = (_Float16*)(fws + off); off += (size_t)N_NODES * 128; // fp16 [20000,256]
  float* h2   = fws + off; off += (size_t)N_NODES * 16;
  float* alS1 = fws + off; off += N_NODES * 4;   // planar [4][N]
  float* alD1 = fws + off; off += N_NODES * 4;   // planar [4][N]
  float* alS2 = fws + off; off += N_NODES;
  float* alD2 = fws + off; off += N_NODES;
  int* cur  = (int*)(fws + off); off += (size_t)N_NODES * CURPAD;
  int* adjS = (int*)(fws + off); off += (size_t)N_NODES * MAXDEG;

  k_init<<<(N_NODES * CURPAD + 255) / 256, 256, 0, stream>>>(cur, W1, W1t);
  k_gemm1<<<dim3(313, 2), 256, 0, stream>>>(x, W1t, as1, ad1, (_Float16*)h1h,
                                            alS1, alD1, ei, cur, adjS);
  k_attn1<<<5000, 256, 0, stream>>>(cur, adjS, h1h, alS1, alD1, b1, heluh);
  k_gemm2<<<313, 256, 0, stream>>>(heluh, W2, as2, ad2, h2, alS2, alD2);
  k_attn2<<<1250, 256, 0, stream>>>(cur, adjS, h2, alS2, alD2, b2, out);
}